// Round 1
// baseline (754.710 us; speedup 1.0000x reference)
//
#include <hip/hip_runtime.h>
#include <hip/hip_cooperative_groups.h>
#include <math.h>

namespace cg = cooperative_groups;

#define NN 10000
#define EE 160000
#define EP 170000          // EE + NN self loops
#define NFEAT 256
#define NHID 128
#define NH 4
#define HF 512             // NH * NHID
#define NCLASS 40

typedef __attribute__((ext_vector_type(8))) short bf8;     // 8 bf16 (4 VGPR) MFMA frag
typedef __attribute__((ext_vector_type(8))) unsigned short u16x8;
typedef __attribute__((ext_vector_type(4))) float f4;

__device__ __forceinline__ float leaky02(float x) { return x >= 0.0f ? x : 0.2f * x; }

__device__ __forceinline__ unsigned short f2bf(float f) {   // RNE
    unsigned u = __builtin_bit_cast(unsigned, f);
    unsigned r = (u + 0x7FFF + ((u >> 16) & 1)) >> 16;
    return (unsigned short)r;
}
__device__ __forceinline__ float bf2f(unsigned short h) {
    return __builtin_bit_cast(float, (unsigned)h << 16);
}

// Bank-swizzled element position within a row of length K (baked into GLOBAL layout
// of MFMA operands so global->LDS staging is a LINEAR copy for global_load_lds).
__device__ __forceinline__ int swz(int row, int c) {
    return ((((c >> 3) ^ (row & 7)) << 3) | (c & 7));
}

// 16B global -> LDS direct DMA
__device__ __forceinline__ void gl_lds16(const unsigned short* g, unsigned short* l)
{
    __builtin_amdgcn_global_load_lds(
        (const __attribute__((address_space(1))) unsigned int*)g,
        (__attribute__((address_space(3))) unsigned int*)l, 16, 0, 0);
}

// cvt section offsets (element counts)
#define C_X   2560000
#define C_EW  (C_X + 32768)
#define C_FW  (C_EW + 131072)      // gat_w + res_w -> fw rows 0..1023
#define C_DW  (C_FW + 5120)        // dec_w [40,128]
#define CVT_U (C_DW / 8)           // 341120 8-elem units (exact)

// ---------------- bf16 MFMA GEMM tile job (32 KB LDS) + LDS-staged epilogue ----------------
// Tile 64x64, 4 waves 2x2, wave 32x32 = 2x2 MFMA tiles. acc += A*B (plain bf16).
// MODE 0: dec  -> outF[row*40+col]+bias (scalar, 40 cols)
// MODE 1: enc  -> relu(v+bias) -> bf16 (swizzled), ld=128
// MODE 2: layer-> bn<512: bf16 xh (natural, outH); 512..1023: bf16 res+biasRG (outL);
//                 1024..1031: a_src/a_dst fp32
template<int MODE, int KTILES>
__device__ void gemm_job(int bx, int by,
    const unsigned short* __restrict__ A, const unsigned short* __restrict__ B,
    const float* __restrict__ bias, float* __restrict__ outF,
    unsigned short* __restrict__ outH, unsigned short* __restrict__ outL,
    float* __restrict__ a_srcW, float* __restrict__ a_dstW, int M,
    unsigned short* smem)
{
    constexpr int K = KTILES * 128;
    const int tid = threadIdx.x;
    unsigned short* sA = smem;
    unsigned short* sB = smem + 8192;

    const int lane = tid & 63, wv = tid >> 6;
    const int wr = (wv >> 1) * 32, wc = (wv & 1) * 32;
    const int bm = bx * 64, bn = by * 64;
    const int r16 = lane & 15, q4 = lane >> 4;

    __syncthreads();   // smem reuse guard vs previous job in this block

    f4 acc[2][2];
#pragma unroll
    for (int i = 0; i < 2; ++i)
#pragma unroll
        for (int j = 0; j < 2; ++j) acc[i][j] = (f4){0.f, 0.f, 0.f, 0.f};

    const int ra0 = wr + r16;
    const int rb0 = wc + r16;

    for (int kt = 0; kt < KTILES; ++kt) {
        if (kt) __syncthreads();
#pragma unroll
        for (int j = 0; j < 4; ++j) {
            int i = tid + j * 256;                    // unit 0..1023
            int row = i >> 4, u = i & 15;
            int arow = min(bm + row, M - 1);
            size_t ga = (size_t)arow * K + kt * 128 + u * 8;
            size_t gb = (size_t)(bn + row) * K + kt * 128 + u * 8;
            int lb = (wv * 64 + j * 256) * 8;         // wave-uniform LDS base
            gl_lds16(A + ga, sA + lb);
            gl_lds16(B + gb, sB + lb);
        }
        __syncthreads();

#pragma unroll
        for (int ks = 0; ks < 4; ++ks) {
            int u = ks * 4 + q4;
            int oa0 = ra0 * 128 + ((u ^ (ra0 & 7)) * 8);
            int ob0 = rb0 * 128 + ((u ^ (rb0 & 7)) * 8);
            int oa1 = oa0 + 16 * 128;
            int ob1 = ob0 + 16 * 128;
            bf8 A0 = *(const bf8*)(sA + oa0);
            bf8 A1 = *(const bf8*)(sA + oa1);
            bf8 B0 = *(const bf8*)(sB + ob0);
            bf8 B1 = *(const bf8*)(sB + ob1);

            acc[0][0] = __builtin_amdgcn_mfma_f32_16x16x32_bf16(A0, B0, acc[0][0], 0, 0, 0);
            acc[0][1] = __builtin_amdgcn_mfma_f32_16x16x32_bf16(A0, B1, acc[0][1], 0, 0, 0);
            acc[1][0] = __builtin_amdgcn_mfma_f32_16x16x32_bf16(A1, B0, acc[1][0], 0, 0, 0);
            acc[1][1] = __builtin_amdgcn_mfma_f32_16x16x32_bf16(A1, B1, acc[1][1], 0, 0, 0);
        }
    }

    const int rbase = q4 * 4;

    if (MODE == 0 || (MODE == 2 && bn >= 1024)) {
        // scalar epilogue: dec (40 cols) / attn columns (8 cols)
#pragma unroll
        for (int i = 0; i < 2; ++i)
#pragma unroll
            for (int j = 0; j < 2; ++j)
#pragma unroll
                for (int r = 0; r < 4; ++r) {
                    int row = bm + wr + i * 16 + rbase + r;
                    int col = bn + wc + j * 16 + r16;
                    if (row >= M) continue;
                    float v = acc[i][j][r];
                    if (MODE == 0) {
                        if (col < NCLASS)
                            outF[(size_t)row * NCLASS + col] = v + bias[col];
                    } else {
                        if (col < 1032) {
                            int h = col - 1024;
                            if (h < 4) a_srcW[row * 4 + h] = v;
                            else       a_dstW[row * 4 + h - 4] = v;
                        }
                    }
                }
        return;
    }

    // ---- staged coalesced epilogue ----
    __syncthreads();
    float* sC = (float*)smem;                 // 64 x 65 fp32 (16.6 KB <= 32 KB)
#pragma unroll
    for (int i = 0; i < 2; ++i)
#pragma unroll
        for (int j = 0; j < 2; ++j)
#pragma unroll
            for (int r = 0; r < 4; ++r)
                sC[(wr + i * 16 + rbase + r) * 65 + (wc + j * 16 + r16)] = acc[i][j][r];
    __syncthreads();

    int row = tid >> 2, seg = tid & 3, c0 = seg * 16;
    int grow = bm + row;
    if (grow < M) {
        float v[16];
#pragma unroll
        for (int k = 0; k < 16; ++k) v[k] = sC[row * 65 + c0 + k];

        if (MODE == 1) {
            unsigned short hs[16];
#pragma unroll
            for (int k = 0; k < 16; ++k)
                hs[k] = f2bf(fmaxf(v[k] + bias[bn + c0 + k], 0.0f));
#pragma unroll
            for (int uu = 0; uu < 2; ++uu) {
                int ug = (bn + c0) / 8 + uu;
                int pu = ug ^ (grow & 7);
                *(u16x8*)(outH + (size_t)grow * 128 + pu * 8) = *(u16x8*)(hs + uu * 8);
            }
        } else {                              // MODE 2, bn < 1024
            if (bn < 512) {                   // xh -> bf16 (natural)
                unsigned short hs[16];
#pragma unroll
                for (int k = 0; k < 16; ++k) hs[k] = f2bf(v[k]);
                *(u16x8*)(outH + (size_t)grow * 512 + bn + c0)     = *(u16x8*)hs;
                *(u16x8*)(outH + (size_t)grow * 512 + bn + c0 + 8) = *(u16x8*)(hs + 8);
            } else {                          // res + (res_b+gat_b) -> bf16 (natural)
                unsigned short hs[16];
#pragma unroll
                for (int k = 0; k < 16; ++k) hs[k] = f2bf(v[k] + bias[bn - 512 + c0 + k]);
                *(u16x8*)(outL + (size_t)grow * 512 + (bn - 512) + c0)     = *(u16x8*)hs;
                *(u16x8*)(outL + (size_t)grow * 512 + (bn - 512) + c0 + 8) = *(u16x8*)(hs + 8);
            }
        }
    }
}

// ------- head-partitioned softmax+gather+residual+ELU+head-mean -> X (bf16, swizzled) ------
// job = (head-major) node-group: head h = job/2500, 4 nodes per job, wave per node.
// Lanes = 4 edge-subgroups x 16 col-lanes; cross-subgroup combine via shfl_xor (no LDS).
__device__ void agg_job(int bx,
    const int* __restrict__ row_ptr, const int* __restrict__ csr,
    const float* __restrict__ a_src, const float* __restrict__ a_dst,
    const unsigned short* __restrict__ xh_b, const unsigned short* __restrict__ resb,
    unsigned short* __restrict__ Xhi)
{
    int h  = bx / 2500;
    int ng = bx - h * 2500;
    int wv = threadIdx.x >> 6, lane = threadIdx.x & 63;
    int d = ng * 4 + wv;                      // 2500*4 = NN exact
    int beg = row_ptr[d], end = row_ptr[d + 1];
    int eg = lane >> 4, c16 = lane & 15;      // edge subgroup / col lane
    int cb = h * 128 + c16 * 8;               // 8 cols of head h
    float ad = a_dst[d * 4 + h];
    u16x8 rv = *(const u16x8*)(resb + (size_t)d * HF + cb);

    float acc[8];
#pragma unroll
    for (int k = 0; k < 8; ++k) acc[k] = 0.0f;
    float ssum = 0.0f;

    int e = beg;
    for (; e + 16 <= end; e += 16) {          // 4 chunks x 4 edges in flight
        int sv[4]; float w[4]; u16x8 v[4];
#pragma unroll
        for (int q = 0; q < 4; ++q) sv[q] = csr[e + q * 4 + eg];
#pragma unroll
        for (int q = 0; q < 4; ++q) v[q] = *(const u16x8*)(xh_b + (size_t)sv[q] * HF + cb);
#pragma unroll
        for (int q = 0; q < 4; ++q) {
            w[q] = __expf(leaky02(a_src[sv[q] * 4 + h] + ad));
            ssum += w[q];
        }
#pragma unroll
        for (int q = 0; q < 4; ++q)
#pragma unroll
            for (int k = 0; k < 8; ++k) acc[k] = fmaf(w[q], bf2f(v[q][k]), acc[k]);
    }
    for (; e + 4 <= end; e += 4) {
        int s = csr[e + eg];
        u16x8 v = *(const u16x8*)(xh_b + (size_t)s * HF + cb);
        float w = __expf(leaky02(a_src[s * 4 + h] + ad));
        ssum += w;
#pragma unroll
        for (int k = 0; k < 8; ++k) acc[k] = fmaf(w, bf2f(v[k]), acc[k]);
    }
    if (e + eg < end) {                       // predicated tail (<4 edges)
        int s = csr[e + eg];
        u16x8 v = *(const u16x8*)(xh_b + (size_t)s * HF + cb);
        float w = __expf(leaky02(a_src[s * 4 + h] + ad));
        ssum += w;
#pragma unroll
        for (int k = 0; k < 8; ++k) acc[k] = fmaf(w, bf2f(v[k]), acc[k]);
    }

    // combine the 4 edge-subgroups (lanes differing in bits 4..5)
#pragma unroll
    for (int off = 16; off <= 32; off <<= 1) {
        ssum += __shfl_xor(ssum, off);
#pragma unroll
        for (int k = 0; k < 8; ++k) acc[k] += __shfl_xor(acc[k], off);
    }

    float inv = 1.0f / ssum;
    float uv[8];
#pragma unroll
    for (int k = 0; k < 8; ++k) {
        float v = fmaf(acc[k], inv, bf2f(rv[k]));
        uv[k] = (v > 0.0f) ? v : expm1f(v);
    }
    float z0 = (uv[0] + uv[1] + uv[2] + uv[3]) * 0.25f;
    float z1 = (uv[4] + uv[5] + uv[6] + uv[7]) * 0.25f;
    if (eg == 0) {
        int col = h * 32 + c16 * 2;           // z-cols of head h (2 per lane, same unit)
        unsigned short h0b = f2bf(z0), h1b = f2bf(z1);
        size_t idx = (size_t)d * NHID + swz(d, col);
        *(unsigned*)(Xhi + idx) = ((unsigned)h1b << 16) | h0b;
    }
}

// ---------------- cooperative mega-kernel: whole pipeline, 7 grid syncs ----------------
struct MegaArgs {
    const float *x, *enc_w, *enc_b, *res_b, *gat_w, *att_src, *att_dst, *gat_b, *dec_w, *dec_b;
    const float *res_w;
    const int* ei;
    float* out;
    float *a_src, *a_dst, *biasRG;
    unsigned short *xh_b, *resb, *Xhi, *xhi, *ewhi, *fwhi, *dwhi;
    int *row_ptr, *csr, *cnt, *cursor;
};

__global__ __launch_bounds__(256, 3)
void mega_k(MegaArgs a)
{
    __shared__ __align__(16) unsigned short smem[2 * 64 * 128];   // 32 KB
    cg::grid_group gg = cg::this_grid();
    const int g   = (int)gridDim.x;
    const int bid = (int)blockIdx.x, tid = (int)threadIdx.x;
    const int gtid = bid * 256 + tid;
    const int gth  = g * 256;

    // ================= P0: zero + cvt + attw + biasRG =================
    {   // zero ONLY regions not fully rewritten below: dec pad rows 40..63, cnt, cursor
        int* dz = (int*)(a.dwhi + 40 * 128);          // 3072 shorts = 1536 ints
        for (int i = gtid; i < 1536; i += gth) dz[i] = 0;
        for (int i = gtid; i < NN; i += gth) { a.cnt[i] = 0; a.cursor[i] = 0; }
    }
    for (int iu = gtid; iu < CVT_U; iu += gth) {      // fp32 -> bf16 (swizzled layouts)
        int i = iu * 8;
        const float* src = nullptr; unsigned short* ph; int j, row, c, Kd;
        if (i < C_X)       { j = i;        src = a.x;     ph = a.xhi;
                             row = j >> 8; c = j & 255; Kd = 256; }
        else if (i < C_EW) { j = i - C_X;  src = a.enc_w; ph = a.ewhi;
                             row = j >> 8; c = j & 255; Kd = 256; }
        else if (i < C_FW) { j = i - C_EW; ph = a.fwhi;
                             row = j >> 7; c = j & 127; Kd = 128; }
        else               { j = i - C_FW; src = a.dec_w; ph = a.dwhi;
                             row = j >> 7; c = j & 127; Kd = 128; }
        float4 v0, v1;
        if (src) { v0 = *(const float4*)(src + j); v1 = *(const float4*)(src + j + 4); }
        else {
            const float* s2 = (j < 65536) ? (a.gat_w + j) : (a.res_w + j - 65536);
            v0 = *(const float4*)s2; v1 = *(const float4*)(s2 + 4);
        }
        float vv[8] = {v0.x, v0.y, v0.z, v0.w, v1.x, v1.y, v1.z, v1.w};
        unsigned short hs[8];
#pragma unroll
        for (int k = 0; k < 8; ++k) hs[k] = f2bf(vv[k]);
        int outp = row * Kd + swz(row, c);
        *(u16x8*)(ph + outp) = *(u16x8*)hs;
    }
    if (bid < 8) {                                    // attn weight rows of fw (+pad zero)
        float* sm = (float*)smem;
        int b = bid, is_dst = b >> 2, h = b & 3;
        const float* att = is_dst ? a.att_dst : a.att_src;
        int k = tid & 127, half = tid >> 7;
        float s = 0.0f;
#pragma unroll 4
        for (int c = half * 64; c < half * 64 + 64; ++c)
            s = fmaf(a.gat_w[(size_t)(h * 128 + c) * 128 + k], att[h * 128 + c], s);
        sm[tid] = s;
        __syncthreads();
        if (tid < 128) {
            float v = sm[tid] + sm[tid + 128];
            int R = 1024 + is_dst * 4 + h;
            a.fwhi[(size_t)R * 128 + swz(R, k)] = f2bf(v);
        }
        for (int i = b * 896 + tid; i < (b + 1) * 896; i += 256)
            a.fwhi[1032 * 128 + i] = 0;
    }
    if (bid == 8) {
        a.biasRG[tid]       = a.res_b[tid]       + a.gat_b[tid];
        a.biasRG[tid + 256] = a.res_b[tid + 256] + a.gat_b[tid + 256];
    }
    gg.sync();

    // ================= P1: enc gemm (314 jobs) || edge count =================
    {
        int gb1 = min(314, g - 128);
        if (bid < gb1) {
            for (int j = bid; j < 314; j += gb1)
                gemm_job<1, 2>(j % 157, j / 157, a.xhi, a.ewhi, a.enc_b,
                               nullptr, a.Xhi, nullptr, nullptr, nullptr, NN, smem);
        } else {
            for (int e = (bid - gb1) * 256 + tid; e < EP; e += (g - gb1) * 256) {
                int d = (e < EE) ? a.ei[EE + e] : (e - EE);
                atomicAdd(&a.cnt[d], 1);
            }
        }
    }
    gg.sync();

    // ================= P2: L1 gemm (2669 jobs) || CSR prefix scan =================
    {
        int gb2 = g - 1;
        if (bid < gb2) {
            int cpb = (2669 + gb2 - 1) / gb2;
            int j0 = bid * cpb, j1 = min(j0 + cpb, 2669);
            for (int j = j0; j < j1; ++j)
                gemm_job<2, 1>(j % 157, j / 157, a.Xhi, a.fwhi, a.biasRG,
                               nullptr, a.xh_b, a.resb, a.a_src, a.a_dst, NN, smem);
        } else {                                      // last block: serial-ish scan
            int* smi = (int*)smem;
            int i0 = tid * 40, i1 = min(i0 + 40, NN);
            int part = 0;
            for (int i = i0; i < i1; ++i) part += a.cnt[i];
            smi[tid] = part;
            __syncthreads();
            for (int off = 1; off < 256; off <<= 1) {
                int v = (tid >= off) ? smi[tid - off] : 0;
                __syncthreads();
                smi[tid] += v;
                __syncthreads();
            }
            int run = smi[tid] - part;
            for (int i = i0; i < i1; ++i) { a.row_ptr[i] = run; run += a.cnt[i]; }
            if (tid == 255) a.row_ptr[NN] = run;
        }
    }
    gg.sync();

    // ================= P3: CSR fill =================
    for (int e = gtid; e < EP; e += gth) {
        int s, d;
        if (e < EE) { s = a.ei[e]; d = a.ei[EE + e]; } else { s = e - EE; d = s; }
        int pos = a.row_ptr[d] + atomicAdd(&a.cursor[d], 1);
        a.csr[pos] = s;
    }
    gg.sync();

    // ================= P4: agg layer 1 (chunked -> keeps head-major L2 locality) =======
    {
        int cpb = (NN + g - 1) / g;
        int j0 = bid * cpb, j1 = min(j0 + cpb, NN);
        for (int j = j0; j < j1; ++j)
            agg_job(j, a.row_ptr, a.csr, a.a_src, a.a_dst, a.xh_b, a.resb, a.Xhi);
    }
    gg.sync();

    // ================= P5: L2 gemm =================
    {
        int cpb = (2669 + g - 1) / g;
        int j0 = bid * cpb, j1 = min(j0 + cpb, 2669);
        for (int j = j0; j < j1; ++j)
            gemm_job<2, 1>(j % 157, j / 157, a.Xhi, a.fwhi, a.biasRG,
                           nullptr, a.xh_b, a.resb, a.a_src, a.a_dst, NN, smem);
    }
    gg.sync();

    // ================= P6: agg layer 2 =================
    {
        int cpb = (NN + g - 1) / g;
        int j0 = bid * cpb, j1 = min(j0 + cpb, NN);
        for (int j = j0; j < j1; ++j)
            agg_job(j, a.row_ptr, a.csr, a.a_src, a.a_dst, a.xh_b, a.resb, a.Xhi);
    }
    gg.sync();

    // ================= P7: decoder =================
    if (bid < 157)
        gemm_job<0, 1>(bid, 0, a.Xhi, a.dwhi, a.dec_b, a.out,
                       nullptr, nullptr, nullptr, nullptr, NN, smem);
}

// ---------------- launcher ----------------
extern "C" void kernel_launch(void* const* d_in, const int* in_sizes, int n_in,
                              void* d_out, int out_size, void* d_ws, size_t ws_size,
                              hipStream_t stream)
{
    (void)in_sizes; (void)n_in; (void)out_size; (void)ws_size;

    MegaArgs a;
    a.x       = (const float*)d_in[0];
    a.ei      = (const int*)d_in[1];
    a.enc_w   = (const float*)d_in[2];
    a.enc_b   = (const float*)d_in[3];
    a.res_w   = (const float*)d_in[4];
    a.res_b   = (const float*)d_in[5];
    a.gat_w   = (const float*)d_in[6];
    a.att_src = (const float*)d_in[7];
    a.att_dst = (const float*)d_in[8];
    a.gat_b   = (const float*)d_in[9];
    a.dec_w   = (const float*)d_in[10];
    a.dec_b   = (const float*)d_in[11];
    a.out     = (float*)d_out;

    char* p = (char*)d_ws;
    auto alloc = [&](size_t bytes) -> void* {
        void* r = (void*)p;
        p += (bytes + 255) & ~(size_t)255;
        return r;
    };
    a.a_src   = (float*)alloc(40000 * 4);
    a.a_dst   = (float*)alloc(40000 * 4);
    a.biasRG  = (float*)alloc(512 * 4);
    a.xh_b    = (unsigned short*)alloc(5120000 * 2);     // [N,512] bf16 (natural)
    a.resb    = (unsigned short*)alloc(5120000 * 2);     // [N,512] bf16 (natural)
    a.Xhi     = (unsigned short*)alloc(1280000 * 2);     // [N,128] bf16 (swizzled)
    a.xhi     = (unsigned short*)alloc(2560000 * 2);     // x [N,256] bf16 (swizzled)
    a.ewhi    = (unsigned short*)alloc(32768 * 2);       // enc_w bf16 (swizzled)
    a.fwhi    = (unsigned short*)alloc(1088 * 128 * 2);  // [1088,128] bf16 (swizzled)
    a.row_ptr = (int*)alloc(10004 * 4);
    a.csr     = (int*)alloc(170000 * 4);
    a.dwhi    = (unsigned short*)alloc(8192 * 2);        // [64,128] padded (swizzled)
    a.cnt     = (int*)alloc(10000 * 4);
    a.cursor  = (int*)alloc(10000 * 4);

    // one cooperative dispatch for the whole pipeline (no memset, no other kernels)
    static int s_mb = 0;                                 // blocks per CU (cached)
    if (s_mb == 0) {
        int mb = 0;
        if (hipOccupancyMaxActiveBlocksPerMultiprocessor(
                &mb, (const void*)mega_k, 256, 0) != hipSuccess || mb < 1)
            mb = 3;                                      // launch_bounds guarantees >=3
        if (mb > 5) mb = 5;                              // LDS 32KB caps at 5 anyway
        if (mb < 2) mb = 2;
        s_mb = mb;
    }
    void* kargs[] = { (void*)&a };
    for (int t = 0; t < 3; ++t) {
        hipError_t err = hipLaunchCooperativeKernel(
            (const void*)mega_k, dim3(256u * (unsigned)s_mb), dim3(256),
            kargs, 0, stream);
        if (err == hipSuccess) break;
        (void)hipGetLastError();                         // clear + retry smaller
        if (s_mb > 1) --s_mb;
    }
}

// Round 2
// 206.523 us; speedup vs baseline: 3.6544x; 3.6544x over previous
//
#include <hip/hip_runtime.h>
#include <math.h>

#define NN 10000
#define EE 160000
#define EP 170000          // EE + NN self loops
#define NFEAT 256
#define NHID 128
#define NH 4
#define HF 512             // NH * NHID
#define NCLASS 40

typedef __attribute__((ext_vector_type(8))) short bf8;     // 8 bf16 (4 VGPR) MFMA frag
typedef __attribute__((ext_vector_type(8))) unsigned short u16x8;
typedef __attribute__((ext_vector_type(4))) float f4;

__device__ __forceinline__ float leaky02(float x) { return x >= 0.0f ? x : 0.2f * x; }

__device__ __forceinline__ unsigned short f2bf(float f) {   // RNE
    unsigned u = __builtin_bit_cast(unsigned, f);
    unsigned r = (u + 0x7FFF + ((u >> 16) & 1)) >> 16;
    return (unsigned short)r;
}
__device__ __forceinline__ float bf2f(unsigned short h) {
    return __builtin_bit_cast(float, (unsigned)h << 16);
}

// Bank-swizzled element position within a row of length K (baked into GLOBAL layout
// of MFMA operands so global->LDS staging is a LINEAR copy for global_load_lds).
__device__ __forceinline__ int swz(int row, int c) {
    return ((((c >> 3) ^ (row & 7)) << 3) | (c & 7));
}

// 16B global -> LDS direct DMA
__device__ __forceinline__ void gl_lds16(const unsigned short* g, unsigned short* l)
{
    __builtin_amdgcn_global_load_lds(
        (const __attribute__((address_space(1))) unsigned int*)g,
        (__attribute__((address_space(3))) unsigned int*)l, 16, 0, 0);
}

// ---------------- fused setup: cvt fw+dw (bf16, swizzled) + biasRG + edge count ----------
// [R1 lesson: cooperative mega-kernel regressed 206->755us — ockl grid.sync costs ~120us
//  per barrier on gfx950 (cross-XCD cacheline + s_sleep backoff). Multi-dispatch kept.]
// x/enc_w conversion removed: the enc GEMM now stages fp32 directly (saves the 10MB pass).
#define CVT_EL 136192              // 131072 (gat_w+res_w) + 5120 (dec_w)
#define CVT_B  67                  // ceil((CVT_EL/8)/256)
#define TOT_B  188                 // CVT_B + 1 bias + 120 count blocks

__global__ __launch_bounds__(256)
void fused0_k(const float* __restrict__ gat_w, const float* __restrict__ res_w,
              const float* __restrict__ dec_w,
              const float* __restrict__ res_b, const float* __restrict__ gat_b,
              const int* __restrict__ ei,
              unsigned short* __restrict__ fwhi, unsigned short* __restrict__ dwhi,
              float* __restrict__ biasRG, int* __restrict__ cnt)
{
    int bId = blockIdx.x, t = threadIdx.x;
    if (bId < CVT_B) {
        int iu = bId * 256 + t;
        int i = iu * 8;
        if (i >= CVT_EL) return;
        const float* src; unsigned short* ph; int j;
        if (i < 131072) { j = i;          ph = fwhi;
                          src = (j < 65536) ? (gat_w + j) : (res_w + j - 65536); }
        else            { j = i - 131072; ph = dwhi; src = dec_w + j; }
        int row = j >> 7, c = j & 127;
        float4 v0 = *(const float4*)src, v1 = *(const float4*)(src + 4);
        float vv[8] = {v0.x, v0.y, v0.z, v0.w, v1.x, v1.y, v1.z, v1.w};
        unsigned short hs[8];
#pragma unroll
        for (int k = 0; k < 8; ++k) hs[k] = f2bf(vv[k]);
        *(u16x8*)(ph + row * 128 + swz(row, c)) = *(u16x8*)hs;
    } else if (bId == CVT_B) {
        biasRG[t]       = res_b[t]       + gat_b[t];
        biasRG[t + 256] = res_b[t + 256] + gat_b[t + 256];
    } else {
        for (int e = (bId - CVT_B - 1) * 256 + t; e < EP; e += (TOT_B - CVT_B - 1) * 256) {
            int d = (e < EE) ? ei[EE + e] : (e - EE);
            atomicAdd(&cnt[d], 1);
        }
    }
}

// ---------------- bf16 MFMA GEMM (32 KB LDS) + LDS-staged epilogue ----------------
// Block 64x64, 4 waves 2x2, wave 32x32 = 2x2 MFMA tiles. acc += A*B (plain bf16).
// F32=true: A,B are fp32 row-major (natural); reg-stage + cvt + swizzled ds_write.
// F32=false: A,B are bf16 with swizzle baked in global layout; linear global_load_lds.
// MODE 0: dec  -> outF[row*40+col]+bias (scalar, 40 cols)
// MODE 1: enc  -> relu(v+bias) -> bf16 (swizzled), ld=128
// MODE 2: layer-> bn<512: bf16 xh (natural, outH) + fused attn partial (atomicAdd a_src/a_dst);
//                 512..1023: bf16 res+biasRG (outL)
// MERGE 1: last y-slice, x==0 runs the CSR prefix scan; MERGE 2: last y-slice fills CSR.
template<int MODE, int KTILES, int MERGE, bool F32>
__global__ __launch_bounds__(256)
void gemm3_k(const void* __restrict__ Ap, const void* __restrict__ Bp,
             const float* __restrict__ bias, float* __restrict__ outF,
             unsigned short* __restrict__ outH, unsigned short* __restrict__ outL,
             float* __restrict__ aS, float* __restrict__ aD,
             const float* __restrict__ attS, const float* __restrict__ attD, int M,
             const int* __restrict__ ei, const int* __restrict__ cnt,
             int* __restrict__ row_ptr, int* __restrict__ cursor, int* __restrict__ csr)
{
    constexpr int K = KTILES * 128;
    __shared__ __align__(16) unsigned short smem[2 * 64 * 128];   // 32 KB
    const int tid = threadIdx.x;

    if (MERGE && blockIdx.y == gridDim.y - 1) {
        if (MERGE == 1) {
            if (blockIdx.x != 0) return;
            int* smi = (int*)smem;
            int i0 = tid * 40, i1 = min(i0 + 40, NN);
            int part = 0;
            for (int i = i0; i < i1; ++i) part += cnt[i];
            smi[tid] = part;
            __syncthreads();
            for (int off = 1; off < 256; off <<= 1) {
                int v = (tid >= off) ? smi[tid - off] : 0;
                __syncthreads();
                smi[tid] += v;
                __syncthreads();
            }
            int run = smi[tid] - part;
            for (int i = i0; i < i1; ++i) { row_ptr[i] = run; run += cnt[i]; }
            if (tid == 255) row_ptr[NN] = run;
        } else {
            int stride = gridDim.x * 256;
            for (int e = blockIdx.x * 256 + tid; e < EP; e += stride) {
                int s, d;
                if (e < EE) { s = ei[e]; d = ei[EE + e]; } else { s = e - EE; d = s; }
                int pos = row_ptr[d] + atomicAdd(&cursor[d], 1);
                csr[pos] = s;
            }
        }
        return;
    }

    unsigned short* sA = smem;
    unsigned short* sB = smem + 8192;

    const int lane = tid & 63, wv = tid >> 6;
    const int wr = (wv >> 1) * 32, wc = (wv & 1) * 32;
    const int bm = blockIdx.x * 64, bn = blockIdx.y * 64;
    const int r16 = lane & 15, q4 = lane >> 4;

    f4 acc[2][2];
#pragma unroll
    for (int i = 0; i < 2; ++i)
#pragma unroll
        for (int j = 0; j < 2; ++j) acc[i][j] = (f4){0.f, 0.f, 0.f, 0.f};

    const int ra0 = wr + r16;
    const int rb0 = wc + r16;

    for (int kt = 0; kt < KTILES; ++kt) {
        if (kt) __syncthreads();
        if (!F32) {
            const unsigned short* A = (const unsigned short*)Ap;
            const unsigned short* B = (const unsigned short*)Bp;
#pragma unroll
            for (int j = 0; j < 4; ++j) {
                int i = tid + j * 256;                    // unit 0..1023
                int row = i >> 4, u = i & 15;
                int arow = min(bm + row, M - 1);
                size_t ga = (size_t)arow * K + kt * 128 + u * 8;
                size_t gb = (size_t)(bn + row) * K + kt * 128 + u * 8;
                int lb = (wv * 64 + j * 256) * 8;         // wave-uniform LDS base
                gl_lds16(A + ga, sA + lb);
                gl_lds16(B + gb, sB + lb);
            }
        } else {
            const float* A = (const float*)Ap;
            const float* B = (const float*)Bp;
#pragma unroll
            for (int j = 0; j < 4; ++j) {
                int i = tid + j * 256;
                int row = i >> 4, u = i & 15;             // logical unit u
                int arow = min(bm + row, M - 1);
                const float* pa = A + (size_t)arow * K + kt * 128 + u * 8;
                const float* pb = B + (size_t)(bn + row) * K + kt * 128 + u * 8;
                float4 a0 = *(const float4*)pa, a1 = *(const float4*)(pa + 4);
                float4 b0 = *(const float4*)pb, b1 = *(const float4*)(pb + 4);
                float av[8] = {a0.x, a0.y, a0.z, a0.w, a1.x, a1.y, a1.z, a1.w};
                float bv[8] = {b0.x, b0.y, b0.z, b0.w, b1.x, b1.y, b1.z, b1.w};
                unsigned short ha[8], hb[8];
#pragma unroll
                for (int k = 0; k < 8; ++k) { ha[k] = f2bf(av[k]); hb[k] = f2bf(bv[k]); }
                int off = row * 128 + ((u ^ (row & 7)) * 8);   // local-row swizzle slot
                *(u16x8*)(sA + off) = *(u16x8*)ha;
                *(u16x8*)(sB + off) = *(u16x8*)hb;
            }
        }
        __syncthreads();

#pragma unroll
        for (int ks = 0; ks < 4; ++ks) {
            int u = ks * 4 + q4;
            int oa0 = ra0 * 128 + ((u ^ (ra0 & 7)) * 8);
            int ob0 = rb0 * 128 + ((u ^ (rb0 & 7)) * 8);
            int oa1 = oa0 + 16 * 128;
            int ob1 = ob0 + 16 * 128;
            bf8 A0 = *(const bf8*)(sA + oa0);
            bf8 A1 = *(const bf8*)(sA + oa1);
            bf8 B0 = *(const bf8*)(sB + ob0);
            bf8 B1 = *(const bf8*)(sB + ob1);

            acc[0][0] = __builtin_amdgcn_mfma_f32_16x16x32_bf16(A0, B0, acc[0][0], 0, 0, 0);
            acc[0][1] = __builtin_amdgcn_mfma_f32_16x16x32_bf16(A0, B1, acc[0][1], 0, 0, 0);
            acc[1][0] = __builtin_amdgcn_mfma_f32_16x16x32_bf16(A1, B0, acc[1][0], 0, 0, 0);
            acc[1][1] = __builtin_amdgcn_mfma_f32_16x16x32_bf16(A1, B1, acc[1][1], 0, 0, 0);
        }
    }

    const int rbase = q4 * 4;

    if (MODE == 0) {
        // scalar epilogue: dec (40 cols)
#pragma unroll
        for (int i = 0; i < 2; ++i)
#pragma unroll
            for (int j = 0; j < 2; ++j)
#pragma unroll
                for (int r = 0; r < 4; ++r) {
                    int row = bm + wr + i * 16 + rbase + r;
                    int col = bn + wc + j * 16 + r16;
                    if (row >= M || col >= NCLASS) continue;
                    outF[(size_t)row * NCLASS + col] = acc[i][j][r] + bias[col];
                }
        return;
    }

    // ---- staged coalesced epilogue ----
    __syncthreads();
    float* sC = (float*)smem;                 // 64 x 65 fp32 (16.6 KB <= 32 KB)
#pragma unroll
    for (int i = 0; i < 2; ++i)
#pragma unroll
        for (int j = 0; j < 2; ++j)
#pragma unroll
            for (int r = 0; r < 4; ++r)
                sC[(wr + i * 16 + rbase + r) * 65 + (wc + j * 16 + r16)] = acc[i][j][r];
    __syncthreads();

    int row = tid >> 2, seg = tid & 3, c0 = seg * 16;
    int grow = bm + row;
    if (grow < M) {
        float v[16];
#pragma unroll
        for (int k = 0; k < 16; ++k) v[k] = sC[row * 65 + c0 + k];

        if (MODE == 1) {
            unsigned short hs[16];
#pragma unroll
            for (int k = 0; k < 16; ++k)
                hs[k] = f2bf(fmaxf(v[k] + bias[bn + c0 + k], 0.0f));
#pragma unroll
            for (int uu = 0; uu < 2; ++uu) {
                int ug = (bn + c0) / 8 + uu;
                int pu = ug ^ (grow & 7);
                *(u16x8*)(outH + (size_t)grow * 128 + pu * 8) = *(u16x8*)(hs + uu * 8);
            }
        } else {                              // MODE 2
            if (bn < 512) {                   // xh -> bf16 (natural) + fused attn partial
                unsigned short hs[16];
#pragma unroll
                for (int k = 0; k < 16; ++k) hs[k] = f2bf(v[k]);
                *(u16x8*)(outH + (size_t)grow * 512 + bn + c0)     = *(u16x8*)hs;
                *(u16x8*)(outH + (size_t)grow * 512 + bn + c0 + 8) = *(u16x8*)(hs + 8);
                // attn partial: fp32 v . att_vec (this 64-col slice is within one head)
                float ps = 0.0f, pd = 0.0f;
#pragma unroll
                for (int k = 0; k < 16; ++k) {
                    ps = fmaf(v[k], attS[bn + c0 + k], ps);
                    pd = fmaf(v[k], attD[bn + c0 + k], pd);
                }
                ps += __shfl_xor(ps, 1); ps += __shfl_xor(ps, 2);
                pd += __shfl_xor(pd, 1); pd += __shfl_xor(pd, 2);
                if (seg == 0) {
                    int h = bn >> 7;
                    atomicAdd(&aS[grow * 4 + h], ps);
                    atomicAdd(&aD[grow * 4 + h], pd);
                }
            } else {                          // res + (res_b+gat_b) -> bf16 (natural)
                unsigned short hs[16];
#pragma unroll
                for (int k = 0; k < 16; ++k) hs[k] = f2bf(v[k] + bias[bn - 512 + c0 + k]);
                *(u16x8*)(outL + (size_t)grow * 512 + (bn - 512) + c0)     = *(u16x8*)hs;
                *(u16x8*)(outL + (size_t)grow * 512 + (bn - 512) + c0 + 8) = *(u16x8*)(hs + 8);
            }
        }
    }
}

// ------- head-partitioned softmax+gather+residual+ELU+head-mean -> X (bf16, swizzled) ------
// Block bx: head h = bx/2500 (head-major launch order -> each quarter of the dispatch
// works a 2.56 MB xh slice that fits per-XCD L2). Wave per node; lanes = 4 edge-subgroups
// x 16 col-lanes, so ONE wave-load covers 4 edges' 256B head-rows. Cross-subgroup combine
// via shfl_xor (no LDS). [R17 lesson: h=bx&3 XCD-pinning + 32-edge unroll both regress.]
__global__ __launch_bounds__(256)
void agg_k(const int* __restrict__ row_ptr, const int* __restrict__ csr,
           const float* __restrict__ a_src, const float* __restrict__ a_dst,
           const unsigned short* __restrict__ xh_b, const unsigned short* __restrict__ resb,
           unsigned short* __restrict__ Xhi)
{
    int bx = blockIdx.x;
    int h  = bx / 2500;
    int ng = bx - h * 2500;
    int wv = threadIdx.x >> 6, lane = threadIdx.x & 63;
    int d = ng * 4 + wv;                      // 2500*4 = NN exact
    int beg = row_ptr[d], end = row_ptr[d + 1];
    int eg = lane >> 4, c16 = lane & 15;      // edge subgroup / col lane
    int cb = h * 128 + c16 * 8;               // 8 cols of head h
    float ad = a_dst[d * 4 + h];
    u16x8 rv = *(const u16x8*)(resb + (size_t)d * HF + cb);

    float acc[8];
#pragma unroll
    for (int k = 0; k < 8; ++k) acc[k] = 0.0f;
    float ssum = 0.0f;

    int e = beg;
    for (; e + 16 <= end; e += 16) {          // 4 chunks x 4 edges in flight
        int sv[4]; float w[4]; u16x8 v[4];
#pragma unroll
        for (int q = 0; q < 4; ++q) sv[q] = csr[e + q * 4 + eg];
#pragma unroll
        for (int q = 0; q < 4; ++q) v[q] = *(const u16x8*)(xh_b + (size_t)sv[q] * HF + cb);
#pragma unroll
        for (int q = 0; q < 4; ++q) {
            w[q] = __expf(leaky02(a_src[sv[q] * 4 + h] + ad));
            ssum += w[q];
        }
#pragma unroll
        for (int q = 0; q < 4; ++q)
#pragma unroll
            for (int k = 0; k < 8; ++k) acc[k] = fmaf(w[q], bf2f(v[q][k]), acc[k]);
    }
    for (; e + 4 <= end; e += 4) {
        int s = csr[e + eg];
        u16x8 v = *(const u16x8*)(xh_b + (size_t)s * HF + cb);
        float w = __expf(leaky02(a_src[s * 4 + h] + ad));
        ssum += w;
#pragma unroll
        for (int k = 0; k < 8; ++k) acc[k] = fmaf(w, bf2f(v[k]), acc[k]);
    }
    if (e + eg < end) {                       // predicated tail (<4 edges)
        int s = csr[e + eg];
        u16x8 v = *(const u16x8*)(xh_b + (size_t)s * HF + cb);
        float w = __expf(leaky02(a_src[s * 4 + h] + ad));
        ssum += w;
#pragma unroll
        for (int k = 0; k < 8; ++k) acc[k] = fmaf(w, bf2f(v[k]), acc[k]);
    }

    // combine the 4 edge-subgroups (lanes differing in bits 4..5)
#pragma unroll
    for (int off = 16; off <= 32; off <<= 1) {
        ssum += __shfl_xor(ssum, off);
#pragma unroll
        for (int k = 0; k < 8; ++k) acc[k] += __shfl_xor(acc[k], off);
    }

    float inv = 1.0f / ssum;
    float uv[8];
#pragma unroll
    for (int k = 0; k < 8; ++k) {
        float v = fmaf(acc[k], inv, bf2f(rv[k]));
        uv[k] = (v > 0.0f) ? v : expm1f(v);
    }
    float z0 = (uv[0] + uv[1] + uv[2] + uv[3]) * 0.25f;
    float z1 = (uv[4] + uv[5] + uv[6] + uv[7]) * 0.25f;
    if (eg == 0) {
        int col = h * 32 + c16 * 2;           // z-cols of head h (2 per lane, same unit)
        unsigned short h0b = f2bf(z0), h1b = f2bf(z1);
        size_t idx = (size_t)d * NHID + swz(d, col);
        *(unsigned*)(Xhi + idx) = ((unsigned)h1b << 16) | h0b;
    }
}

// ---------------- launcher ----------------
extern "C" void kernel_launch(void* const* d_in, const int* in_sizes, int n_in,
                              void* d_out, int out_size, void* d_ws, size_t ws_size,
                              hipStream_t stream)
{
    const float* x       = (const float*)d_in[0];
    const int*   ei      = (const int*)d_in[1];
    const float* enc_w   = (const float*)d_in[2];
    const float* enc_b   = (const float*)d_in[3];
    const float* res_w   = (const float*)d_in[4];
    const float* res_b   = (const float*)d_in[5];
    const float* gat_w   = (const float*)d_in[6];
    const float* att_src = (const float*)d_in[7];
    const float* att_dst = (const float*)d_in[8];
    const float* gat_b   = (const float*)d_in[9];
    const float* dec_w   = (const float*)d_in[10];
    const float* dec_b   = (const float*)d_in[11];
    float* out = (float*)d_out;

    char* p = (char*)d_ws;
    auto alloc = [&](size_t bytes) -> void* {
        void* r = (void*)p;
        p += (bytes + 255) & ~(size_t)255;
        return r;
    };
    float* biasRG = (float*)alloc(512 * 4);
    unsigned short* xh_b = (unsigned short*)alloc(5120000 * 2);     // [N,512] bf16 (natural)
    unsigned short* resb = (unsigned short*)alloc(5120000 * 2);     // [N,512] bf16 (natural)
    unsigned short* Xhi  = (unsigned short*)alloc(1280000 * 2);     // [N,128] bf16 (swizzled)
    unsigned short* fwhi = (unsigned short*)alloc(1024 * 128 * 2);  // gat_w+res_w (swizzled)
    int* row_ptr = (int*)alloc(10004 * 4);
    int* csr     = (int*)alloc(170000 * 4);
    // ---- zero zone (single memset): padded dec W + cnt + cursor + attn accumulators ----
    char* zbase = p;
    unsigned short* dwhi = (unsigned short*)alloc(8192 * 2);        // [64,128] padded (swizzled)
    int* cnt    = (int*)alloc(10000 * 4);
    int* cursor = (int*)alloc(10000 * 4);
    float* aS1  = (float*)alloc(40000 * 4);
    float* aD1  = (float*)alloc(40000 * 4);
    float* aS2  = (float*)alloc(40000 * 4);
    float* aD2  = (float*)alloc(40000 * 4);
    size_t zbytes = (size_t)(p - zbase);

    hipMemsetAsync(zbase, 0, zbytes, stream);

    // setup: weight conversions + biasRG + edge count (one dispatch)
    fused0_k<<<TOT_B, 256, 0, stream>>>(
        gat_w, res_w, dec_w, res_b, gat_b, ei, fwhi, dwhi, biasRG, cnt);

    // encoder gemm: fp32 A/B direct (+ merged CSR prefix scan in last y-slice)
    gemm3_k<1, 2, 1, true><<<dim3(157, 3), 256, 0, stream>>>(
        x, enc_w, enc_b, nullptr, Xhi, nullptr, nullptr, nullptr, nullptr, nullptr, NN,
        nullptr, cnt, row_ptr, nullptr, nullptr);

    // layer 1: fused gemm + attn partials (+ merged fill_csr in last y-slice)
    gemm3_k<2, 1, 2, false><<<dim3(157, 17), 256, 0, stream>>>(
        Xhi, fwhi, biasRG, nullptr, xh_b, resb, aS1, aD1, att_src, att_dst, NN,
        ei, nullptr, row_ptr, cursor, csr);
    agg_k<<<10000, 256, 0, stream>>>(row_ptr, csr, aS1, aD1, xh_b, resb, Xhi);

    // layer 2
    gemm3_k<2, 1, 0, false><<<dim3(157, 16), 256, 0, stream>>>(
        Xhi, fwhi, biasRG, nullptr, xh_b, resb, aS2, aD2, att_src, att_dst, NN,
        nullptr, nullptr, nullptr, nullptr, nullptr);
    agg_k<<<10000, 256, 0, stream>>>(row_ptr, csr, aS2, aD2, xh_b, resb, Xhi);

    // decoder
    gemm3_k<0, 1, 0, false><<<dim3(157, 1), 256, 0, stream>>>(
        Xhi, dwhi, dec_b, out, nullptr, nullptr, nullptr, nullptr, nullptr, nullptr, NN,
        nullptr, nullptr, nullptr, nullptr, nullptr);
}